// Round 7
// baseline (374.530 us; speedup 1.0000x reference)
//
#include <hip/hip_runtime.h>
#include <stdint.h>

// PCLayer closed form, 5-launch route (r7):
//   conv_all : tb = bf16(t-b) [8192,3072], WTb = bf16(W)^T, Wb = bf16(W)
//   E        : Ef(fp32)+Eb(bf16) = lr * WTb @ WTb^T   (one-shot, EPI 5)
//   S''      : Spb = bf16(120*(Eb@Eb^T) - 45*Ef)      (one-shot, EPI 4)
//   WMT      : WMTb = bf16(lr*Spb@Wb^T + 0.01*WTb)    (one-shot, EPI 3)
//   big      : out = tb @ WMT^T  [8192,768] fp32      (B direct from L2)
// r7 vs r6:
//  - conv-stuffing reverted (tails inherited 2/CU LDS occupancy -> ~12
//    serial block-rounds appended per small kernel; cost > benefit).
//    Dedicated conv_all (r1-proven ~25us, no LDS limit on conv part).
//  - big GEMM: B operand (WMT, 4.7MB, L2-resident) read DIRECTLY into
//    registers via global_load_dwordx4 instead of LDS staging. LDS-pipe
//    accounting showed 3456cy ds_read + 1150cy write vs 470cy MFMA per
//    CU-iter -> LDS-bound. B-direct cuts LDS reads 3x (A frags only),
//    staged-per-drain 12KB->4KB, LDS 48KB->8KB. bank-conflict counter
//    (= exactly 4cy/ds_read_b128 in r1/r3/r4/r5 = inherent) predicts
//    ~2.4M now (count-driven).
//  - cvec/bias-fold deleted: tb = t-b already carries bias (bias==0 here
//    anyway; removes latent double-subtract if bias!=0).

typedef short bf16x8 __attribute__((ext_vector_type(8)));   // 8 bf16 = 4 VGPRs
typedef float f32x4  __attribute__((ext_vector_type(4)));
typedef unsigned short u16;
typedef unsigned int uint_as1 __attribute__((address_space(1)));
typedef unsigned int uint_as3 __attribute__((address_space(3)));

__device__ __forceinline__ float bf2f(u16 u) {
  union { unsigned int i; float f; } x; x.i = ((unsigned int)u) << 16; return x.f;
}
__device__ __forceinline__ u16 f2bf(float f) {  // round-to-nearest-even
  union { float f; unsigned int i; } x; x.f = f;
  unsigned int r = x.i + 0x7fffu + ((x.i >> 16) & 1u);
  return (u16)(r >> 16);
}
__device__ __forceinline__ void gl2lds16(const void* g, void* l) {
  // async 16B/lane global->LDS; LDS dst = wave-uniform base + lane*16
  __builtin_amdgcn_global_load_lds((uint_as1*)(uintptr_t)g,
                                   (uint_as3*)(uintptr_t)l, 16, 0, 0);
}

// ---- small GEMM: C[M,N] = alpha * A[M,K] @ B[N,K]^T (bf16, lda=ldb=K),
// one-shot over K. Tile 64 x 128, 4 waves 2x2, BK = 32*NK. 2-barrier loop.
// EPI 3: Cb = f2bf(alpha*acc + beta*bf2f(Yb[idx]))
// EPI 4: Cb = f2bf(alpha*acc + beta*Cf[idx])        (Cf read-only fp32)
// EPI 5: Cf = alpha*acc (fp32)  AND  Cb = f2bf(same)
template<int NK, int EPI>
__global__ __launch_bounds__(256, 2)
void gemm_lds(const u16* __restrict__ A, const u16* __restrict__ B,
              float* __restrict__ Cf, u16* __restrict__ Cb,
              const u16* __restrict__ Yb, float alpha, float beta,
              int K, int ldc)
{
  __shared__ u16 As[64 * 32 * NK];
  __shared__ u16 Bs[128 * 32 * NK];
  const int tid = threadIdx.x, w = tid >> 6, lane = tid & 63;
  const int lm = lane & 15, quad = lane >> 4;
  const int wm = w & 1, wn = w >> 1;
  const int m0 = blockIdx.x * 64, n0 = blockIdx.y * 128;
  const int r = lane >> 2, q = lane & 3;
  const u16* Ag = A + (long)(m0 + w * 16 + r) * K + q * 8;
  const u16* Bg = B + (long)(n0 + w * 32 + r) * K + q * 8;
  u16* Asl = As + w * 16 * 32;   // wave-uniform stage bases
  u16* Bsl = Bs + w * 1024;

  f32x4 acc[2][4] = {};

  for (int kk = 0; kk < K; kk += 32 * NK) {
#pragma unroll
    for (int h = 0; h < NK; ++h) {
      gl2lds16(Ag + kk + h * 32, Asl + h * 2048);
      gl2lds16(Bg + kk + h * 32, Bsl + h * 4096);
      gl2lds16(Bg + 16 * (long)K + kk + h * 32, Bsl + h * 4096 + 512);
    }
    __syncthreads();
#pragma unroll
    for (int h = 0; h < NK; ++h) {
      bf16x8 af[2], bv[4];
#pragma unroll
      for (int i = 0; i < 2; ++i)
        af[i] = *(const bf16x8*)(As + h * 2048 +
                                 (wm * 32 + i * 16 + lm) * 32 + quad * 8);
#pragma unroll
      for (int j = 0; j < 4; ++j)
        bv[j] = *(const bf16x8*)(Bs + h * 4096 +
                                 (wn * 64 + j * 16 + lm) * 32 + quad * 8);
#pragma unroll
      for (int i = 0; i < 2; ++i)
#pragma unroll
        for (int j = 0; j < 4; ++j)
          acc[i][j] = __builtin_amdgcn_mfma_f32_16x16x32_bf16(af[i], bv[j],
                                                              acc[i][j], 0, 0, 0);
    }
    __syncthreads();
  }

  // C/D layout (m89-verified): col = lane&15, row = quad*4 + reg
  const int rbase = m0 + wm * 32 + quad * 4;
  const int cbase = n0 + wn * 64 + lm;
#pragma unroll
  for (int i = 0; i < 2; ++i)
#pragma unroll
    for (int j = 0; j < 4; ++j) {
      const int col = cbase + j * 16;
#pragma unroll
      for (int rr = 0; rr < 4; ++rr) {
        const long idx = (long)(rbase + i * 16 + rr) * ldc + col;
        const float v = alpha * acc[i][j][rr];
        if constexpr (EPI == 3) {
          Cb[idx] = f2bf(v + beta * bf2f(Yb[idx]));
        } else if constexpr (EPI == 4) {
          Cb[idx] = f2bf(v + beta * Cf[idx]);
        } else {  // EPI 5
          Cf[idx] = v;
          Cb[idx] = f2bf(v);
        }
      }
    }
}

// ---- conv_all (r1-proven): tb = bf16(t - b) [blocks 0..24575];
// WTb = bf16(W)^T via LDS-tiled transpose + Wb = bf16(W) [blocks 24576..25151]
__global__ void conv_all(const float* __restrict__ t, const float* __restrict__ bias,
                         const float* __restrict__ W, u16* __restrict__ tb,
                         u16* __restrict__ WTb, u16* __restrict__ Wb)
{
  __shared__ u16 lds[64 * 72];              // [i_local][o_local], stride 72
  const int bx = blockIdx.x, tid = threadIdx.x;
  if (bx < 24576) {                         // t: 6,291,456 float4
    const long i4 = (long)bx * 256 + tid;
    const float4 v = ((const float4*)t)[i4];
    const float4 bb = ((const float4*)bias)[(int)(i4 % 768)];
    ushort4 o;
    o.x = f2bf(v.x - bb.x); o.y = f2bf(v.y - bb.y);
    o.z = f2bf(v.z - bb.z); o.w = f2bf(v.w - bb.w);
    ((ushort4*)tb)[i4] = o;
  } else {
    const int bt = bx - 24576;              // tile (to, ti): o0 = to*64, i0 = ti*64
    const int o0 = (bt / 12) * 64, i0 = (bt % 12) * 64;
    const int ol = tid >> 2, cg = tid & 3;  // 64 o-rows, 4 col-groups
#pragma unroll
    for (int p = 0; p < 4; ++p) {           // 16 float4 per o-row
      const float4 v = *(const float4*)(W + (long)(o0 + ol) * 768 + i0 + (cg + p * 4) * 4);
      const int ib = (cg + p * 4) * 4;
      lds[(ib + 0) * 72 + ol] = f2bf(v.x);
      lds[(ib + 1) * 72 + ol] = f2bf(v.y);
      lds[(ib + 2) * 72 + ol] = f2bf(v.z);
      lds[(ib + 3) * 72 + ol] = f2bf(v.w);
      ushort4 wo;
      wo.x = f2bf(v.x); wo.y = f2bf(v.y); wo.z = f2bf(v.z); wo.w = f2bf(v.w);
      ((ushort4*)(Wb + (long)(o0 + ol) * 768 + i0))[cg + p * 4] = wo;
    }
    __syncthreads();
    const int cl = tid >> 2, og = tid & 3;  // 64 i-rows, 4 o-groups of 16
    const u16* src = lds + cl * 72 + og * 16;
    u16* dst = WTb + (long)(i0 + cl) * 3072 + o0 + og * 16;
    ((ushort4*)dst)[0] = ((const ushort4*)src)[0];
    ((ushort4*)dst)[1] = ((const ushort4*)src)[1];
    ((ushort4*)dst)[2] = ((const ushort4*)src)[2];
    ((ushort4*)dst)[3] = ((const ushort4*)src)[3];
  }
}

// ---- big GEMM: out[8192,768] = tb @ WMT^T  (fp32 out)
// TM=64 x BN=128, 4 waves 2x2, BK=64. A (tb, HBM-streamed) staged via gl2lds
// into 8KB LDS; B (WMT, 4.7MB L2-resident) loaded DIRECTLY into registers
// (global_load_dwordx4, 16B/lane, rows n0+wn*64+j*16+lm). Per CU-iter LDS
// drops ~4600cy -> ~900cy; barrier drain waits only 4KB of A staging.
// Grid 128x6 = 768 = 3 blocks/CU (x fastest => same-bx blocks share A-panel
// and land 128 apart = same XCD: free L2 A-reuse).
__global__ __launch_bounds__(256, 3)
void gemm_big(const u16* __restrict__ A, const u16* __restrict__ B,
              float* __restrict__ out)
{
  __shared__ u16 As[2][64 * 32];         // 8KB: [h][row64][k32]
  const int tid = threadIdx.x, w = tid >> 6, lane = tid & 63;
  const int lm = lane & 15, quad = lane >> 4;
  const int wm = w & 1, wn = w >> 1;
  const int m0 = blockIdx.x * 64, n0 = blockIdx.y * 128;
  const int r = lane >> 2, q = lane & 3;
  const u16* Ag = A + (long)(m0 + w * 16 + r) * 3072 + q * 8;
  u16* Asl = (u16*)As[0] + w * 512;      // wave-uniform stage base (h=0)
  // B fragment base: this lane covers rows (n0 + wn*64 + j*16 + lm), 16B at k
  const u16* Bp = B + (long)(n0 + wn * 64 + lm) * 3072 + quad * 8;

  f32x4 acc[2][4] = {};

  for (int kk = 0; kk < 3072; kk += 64) {
    // A stage: 2 gl2lds per wave (h=0,1)
    gl2lds16(Ag + kk,      Asl);
    gl2lds16(Ag + kk + 32, Asl + 2048);
    // B fragments direct from L2 (8 x dwordx4; land under barrier+LDS reads)
    bf16x8 bv[2][4];
#pragma unroll
    for (int h = 0; h < 2; ++h)
#pragma unroll
      for (int j = 0; j < 4; ++j)
        bv[h][j] = *(const bf16x8*)(Bp + (long)(j * 16) * 3072 + kk + h * 32);
    __syncthreads();                     // A(kk) in LDS
#pragma unroll
    for (int h = 0; h < 2; ++h) {
      bf16x8 af[2];
#pragma unroll
      for (int i = 0; i < 2; ++i)
        af[i] = *(const bf16x8*)((const u16*)As[h] +
                                 (wm * 32 + i * 16 + lm) * 32 + quad * 8);
#pragma unroll
      for (int i = 0; i < 2; ++i)
#pragma unroll
        for (int j = 0; j < 4; ++j)
          acc[i][j] = __builtin_amdgcn_mfma_f32_16x16x32_bf16(af[i], bv[h][j],
                                                              acc[i][j], 0, 0, 0);
    }
    __syncthreads();
  }

  // C/D layout (m89-verified): col = lane&15, row = quad*4 + reg
  const int rbase = m0 + wm * 32 + quad * 4;
  const int cbase = n0 + wn * 64 + lm;
#pragma unroll
  for (int i = 0; i < 2; ++i)
#pragma unroll
    for (int j = 0; j < 4; ++j)
#pragma unroll
      for (int rr = 0; rr < 4; ++rr)
        out[(long)(rbase + i * 16 + rr) * 768 + cbase + j * 16] =
            acc[i][j][rr];
}

extern "C" void kernel_launch(void* const* d_in, const int* in_sizes, int n_in,
                              void* d_out, int out_size, void* d_ws, size_t ws_size,
                              hipStream_t stream)
{
  const float* t    = (const float*)d_in[0];   // [8,1024,3072]
  const float* W    = (const float*)d_in[1];   // [3072,768]
  const float* bias = (const float*)d_in[2];   // [3072]
  float* out = (float*)d_out;                  // [8192,768] fp32

  char* p = (char*)d_ws;                       // 69,206,016 B used
  u16*   tb   = (u16*)(p + 0);                 // 50,331,648  bf16 t-b  [8192,3072]
  u16*   WTb  = (u16*)(p + 50331648);          //  4,718,592  bf16 W^T  [768,3072]
  u16*   Wb   = (u16*)(p + 55050240);          //  4,718,592  bf16 W    [3072,768]
  float* Ef   = (float*)(p + 59768832);        //  2,359,296  E fp32    [768,768]
  u16*   Eb   = (u16*)(p + 62128128);          //  1,179,648  bf16 E
  u16*   Spb  = (u16*)(p + 63307776);          //  1,179,648  bf16 S''
  u16*   WMTb = (u16*)(p + 64487424);          //  4,718,592  bf16 WMT [768,3072]

  const float lr = 0.001f;

  // 1. tb + WTb + Wb  (24576 conv blocks + 576 transpose tiles)
  conv_all<<<25152, 256, 0, stream>>>(t, bias, W, tb, WTb, Wb);
  // 2. Ef,Eb = lr * WT @ WT^T : one-shot K=3072, BK=128 (72 blocks, 24 iters)
  gemm_lds<4, 5><<<dim3(12, 6), 256, 0, stream>>>(
      WTb, WTb, Ef, Eb, nullptr, lr, 0.f, 3072, 768);
  // 3. Spb = bf16(120*(Eb@Eb^T) - 45*Ef) : K=768, BK=128 (72 blocks, 6 iters)
  gemm_lds<4, 4><<<dim3(12, 6), 256, 0, stream>>>(
      Eb, Eb, Ef, Spb, nullptr, 120.f, -45.f, 768, 768);
  // 4. WMTb = bf16(lr*Spb@Wb^T + 0.01*WTb) : K=768 (288 blocks, 6 iters)
  gemm_lds<4, 3><<<dim3(12, 24), 256, 0, stream>>>(
      Spb, Wb, nullptr, WMTb, WTb, lr, 0.01f, 768, 3072);
  // 5. out = tb @ WMT^T : grid 128x6 = 768 blocks, B-direct-from-L2
  gemm_big<<<dim3(128, 6), 256, 0, stream>>>(tb, WMTb, out);
}

// Round 8
// 275.663 us; speedup vs baseline: 1.3587x; 1.3587x over previous
//
#include <hip/hip_runtime.h>
#include <stdint.h>

// PCLayer closed form, 5-launch route (r8):
//   conv_all : tb = bf16(t-b) [8192,3072], WTb = bf16(W)^T, Wb = bf16(W)
//   E        : Ef(fp32)+Eb(bf16) = lr * WTb @ WTb^T   (EPI 5)
//   S''      : Spb = bf16(120*(Eb@Eb^T) - 45*Ef)      (EPI 4)
//   WMT      : WMTb = bf16(lr*Spb@Wb^T + 0.01*WTb)    (EPI 3)
//   big      : out = tb @ WMT^T  [8192,768] fp32      (EPI 6)
// r8 vs r7: B-direct-from-L2 reverted (156us: scattered per-lane L2 loads on
// the MFMA critical path). ALL GEMMs now use the catalog's minimum-2-phase
// pipelined template (T3/T4, m248-verified): double-buffered LDS, per iter
//   STAGE(k+1)->buf^1 ; ds_read+MFMA(k) from buf ; vmcnt(0) LATE ; s_barrier
// vs the old structure's stage->drain->compute which ate the full ~600-900cy
// staging latency on every one of 48 iterations (m233: that drain = 72% of
// 2-phase time; invariant 64-69us across r0-r6 variants regardless of tile/
// occupancy). WAR safety: end-of-iter barrier guarantees all waves finished
// reading buf[cur^1] before next iter's STAGE overwrites it.
// LDS 2 x (8KB A + 16KB B) = 48KB -> 3 blocks/CU, launch_bounds(256,3).

typedef short bf16x8 __attribute__((ext_vector_type(8)));   // 8 bf16 = 4 VGPRs
typedef float f32x4  __attribute__((ext_vector_type(4)));
typedef unsigned short u16;
typedef unsigned int uint_as1 __attribute__((address_space(1)));
typedef unsigned int uint_as3 __attribute__((address_space(3)));

__device__ __forceinline__ float bf2f(u16 u) {
  union { unsigned int i; float f; } x; x.i = ((unsigned int)u) << 16; return x.f;
}
__device__ __forceinline__ u16 f2bf(float f) {  // round-to-nearest-even
  union { float f; unsigned int i; } x; x.f = f;
  unsigned int r = x.i + 0x7fffu + ((x.i >> 16) & 1u);
  return (u16)(r >> 16);
}
__device__ __forceinline__ void gl2lds16(const void* g, void* l) {
  // async 16B/lane global->LDS; LDS dst = wave-uniform base + lane*16
  __builtin_amdgcn_global_load_lds((uint_as1*)(uintptr_t)g,
                                   (uint_as3*)(uintptr_t)l, 16, 0, 0);
}

// ---- pipelined GEMM: C[M,N] = alpha * A[M,K] @ B[N,K]^T (bf16, lda=ldb=K)
// Tile 64 x 128, 4 waves 2x2, BK=64, double-buffered LDS, 1 barrier/iter,
// late vmcnt drain (stage latency hidden under ds_read+MFMA).
// EPI 3: Cb = f2bf(alpha*acc + beta*bf2f(Yb[idx]))
// EPI 4: Cb = f2bf(alpha*acc + beta*Cf[idx])        (Cf read-only fp32)
// EPI 5: Cf = alpha*acc (fp32)  AND  Cb = f2bf(same)
// EPI 6: Cf = alpha*acc (fp32 only; big-GEMM output)
template<int EPI>
__global__ __launch_bounds__(256, 3)
void gemm_pipe(const u16* __restrict__ A, const u16* __restrict__ B,
               float* __restrict__ Cf, u16* __restrict__ Cb,
               const u16* __restrict__ Yb, float alpha, float beta,
               int K, int ldc)
{
  __shared__ u16 As[2][64 * 64];    // 2 x 8KB  [buf][h*2048 + row16*... ] (m97 layout)
  __shared__ u16 Bs[2][128 * 64];   // 2 x 16KB
  const int tid = threadIdx.x, w = tid >> 6, lane = tid & 63;
  const int lm = lane & 15, quad = lane >> 4;
  const int wm = w & 1, wn = w >> 1;
  const int m0 = blockIdx.x * 64, n0 = blockIdx.y * 128;
  const int r = lane >> 2, q = lane & 3;
  const u16* Ag = A + (long)(m0 + w * 16 + r) * K + q * 8;
  const u16* Bg = B + (long)(n0 + w * 32 + r) * K + q * 8;
  const int nIter = K >> 6;

  f32x4 acc[2][4] = {};

  // stage one 64-wide K-slab of A(64 rows) + B(128 rows) into buffer b
#define STAGE(kk, b)                                                         \
  {                                                                          \
    _Pragma("unroll")                                                        \
    for (int h = 0; h < 2; ++h) {                                            \
      gl2lds16(Ag + (kk) + h * 32, As[b] + w * 512 + h * 2048);              \
      gl2lds16(Bg + (kk) + h * 32, Bs[b] + w * 1024 + h * 4096);             \
      gl2lds16(Bg + 16 * (long)K + (kk) + h * 32,                            \
               Bs[b] + w * 1024 + h * 4096 + 512);                           \
    }                                                                        \
  }

  // prologue: tile 0 -> buf 0, drain, barrier
  STAGE(0, 0)
  asm volatile("s_waitcnt vmcnt(0)" ::: "memory");
  __builtin_amdgcn_sched_barrier(0);
  __builtin_amdgcn_s_barrier();
  __builtin_amdgcn_sched_barrier(0);

  int cur = 0;
  for (int k = 0; k < nIter; ++k) {
    if (k + 1 < nIter) STAGE((k + 1) * 64, cur ^ 1)   // issue early
    const u16* Asb = As[cur];
    const u16* Bsb = Bs[cur];
#pragma unroll
    for (int h = 0; h < 2; ++h) {
      bf16x8 af[2], bv[4];
#pragma unroll
      for (int i = 0; i < 2; ++i)
        af[i] = *(const bf16x8*)(Asb + h * 2048 +
                                 (wm * 32 + i * 16 + lm) * 32 + quad * 8);
#pragma unroll
      for (int j = 0; j < 4; ++j)
        bv[j] = *(const bf16x8*)(Bsb + h * 4096 +
                                 (wn * 64 + j * 16 + lm) * 32 + quad * 8);
#pragma unroll
      for (int i = 0; i < 2; ++i)
#pragma unroll
        for (int j = 0; j < 4; ++j)
          acc[i][j] = __builtin_amdgcn_mfma_f32_16x16x32_bf16(af[i], bv[j],
                                                              acc[i][j], 0, 0, 0);
    }
    if (k + 1 < nIter) {
      // drain LATE: stage(k+1) latency ran concurrent with ds_read+MFMA(k)
      asm volatile("s_waitcnt vmcnt(0)" ::: "memory");
      __builtin_amdgcn_sched_barrier(0);
      __builtin_amdgcn_s_barrier();
      __builtin_amdgcn_sched_barrier(0);
      cur ^= 1;
    }
  }
#undef STAGE

  // C/D layout (m89-verified): col = lane&15, row = quad*4 + reg
  const int rbase = m0 + wm * 32 + quad * 4;
  const int cbase = n0 + wn * 64 + lm;
#pragma unroll
  for (int i = 0; i < 2; ++i)
#pragma unroll
    for (int j = 0; j < 4; ++j) {
      const int col = cbase + j * 16;
#pragma unroll
      for (int rr = 0; rr < 4; ++rr) {
        const long idx = (long)(rbase + i * 16 + rr) * ldc + col;
        const float v = alpha * acc[i][j][rr];
        if constexpr (EPI == 3) {
          Cb[idx] = f2bf(v + beta * bf2f(Yb[idx]));
        } else if constexpr (EPI == 4) {
          Cb[idx] = f2bf(v + beta * Cf[idx]);
        } else if constexpr (EPI == 5) {
          Cf[idx] = v;
          Cb[idx] = f2bf(v);
        } else {  // EPI 6
          Cf[idx] = v;
        }
      }
    }
}

// ---- conv_all (r1-proven): tb = bf16(t - b) [blocks 0..24575];
// WTb = bf16(W)^T via LDS-tiled transpose + Wb = bf16(W) [blocks 24576..25151]
__global__ void conv_all(const float* __restrict__ t, const float* __restrict__ bias,
                         const float* __restrict__ W, u16* __restrict__ tb,
                         u16* __restrict__ WTb, u16* __restrict__ Wb)
{
  __shared__ u16 lds[64 * 72];              // [i_local][o_local], stride 72
  const int bx = blockIdx.x, tid = threadIdx.x;
  if (bx < 24576) {                         // t: 6,291,456 float4
    const long i4 = (long)bx * 256 + tid;
    const float4 v = ((const float4*)t)[i4];
    const float4 bb = ((const float4*)bias)[(int)(i4 % 768)];
    ushort4 o;
    o.x = f2bf(v.x - bb.x); o.y = f2bf(v.y - bb.y);
    o.z = f2bf(v.z - bb.z); o.w = f2bf(v.w - bb.w);
    ((ushort4*)tb)[i4] = o;
  } else {
    const int bt = bx - 24576;              // tile (to, ti): o0 = to*64, i0 = ti*64
    const int o0 = (bt / 12) * 64, i0 = (bt % 12) * 64;
    const int ol = tid >> 2, cg = tid & 3;  // 64 o-rows, 4 col-groups
#pragma unroll
    for (int p = 0; p < 4; ++p) {           // 16 float4 per o-row
      const float4 v = *(const float4*)(W + (long)(o0 + ol) * 768 + i0 + (cg + p * 4) * 4);
      const int ib = (cg + p * 4) * 4;
      lds[(ib + 0) * 72 + ol] = f2bf(v.x);
      lds[(ib + 1) * 72 + ol] = f2bf(v.y);
      lds[(ib + 2) * 72 + ol] = f2bf(v.z);
      lds[(ib + 3) * 72 + ol] = f2bf(v.w);
      ushort4 wo;
      wo.x = f2bf(v.x); wo.y = f2bf(v.y); wo.z = f2bf(v.z); wo.w = f2bf(v.w);
      ((ushort4*)(Wb + (long)(o0 + ol) * 768 + i0))[cg + p * 4] = wo;
    }
    __syncthreads();
    const int cl = tid >> 2, og = tid & 3;  // 64 i-rows, 4 o-groups of 16
    const u16* src = lds + cl * 72 + og * 16;
    u16* dst = WTb + (long)(i0 + cl) * 3072 + o0 + og * 16;
    ((ushort4*)dst)[0] = ((const ushort4*)src)[0];
    ((ushort4*)dst)[1] = ((const ushort4*)src)[1];
    ((ushort4*)dst)[2] = ((const ushort4*)src)[2];
    ((ushort4*)dst)[3] = ((const ushort4*)src)[3];
  }
}

extern "C" void kernel_launch(void* const* d_in, const int* in_sizes, int n_in,
                              void* d_out, int out_size, void* d_ws, size_t ws_size,
                              hipStream_t stream)
{
  const float* t    = (const float*)d_in[0];   // [8,1024,3072]
  const float* W    = (const float*)d_in[1];   // [3072,768]
  const float* bias = (const float*)d_in[2];   // [3072]
  float* out = (float*)d_out;                  // [8192,768] fp32

  char* p = (char*)d_ws;                       // 69,206,016 B used
  u16*   tb   = (u16*)(p + 0);                 // 50,331,648  bf16 t-b  [8192,3072]
  u16*   WTb  = (u16*)(p + 50331648);          //  4,718,592  bf16 W^T  [768,3072]
  u16*   Wb   = (u16*)(p + 55050240);          //  4,718,592  bf16 W    [3072,768]
  float* Ef   = (float*)(p + 59768832);        //  2,359,296  E fp32    [768,768]
  u16*   Eb   = (u16*)(p + 62128128);          //  1,179,648  bf16 E
  u16*   Spb  = (u16*)(p + 63307776);          //  1,179,648  bf16 S''
  u16*   WMTb = (u16*)(p + 64487424);          //  4,718,592  bf16 WMT [768,3072]

  const float lr = 0.001f;

  // 1. tb + WTb + Wb  (24576 conv blocks + 576 transpose tiles)
  conv_all<<<25152, 256, 0, stream>>>(t, bias, W, tb, WTb, Wb);
  // 2. Ef,Eb = lr * WT @ WT^T : K=3072, 48 pipelined iters (72 blocks)
  gemm_pipe<5><<<dim3(12, 6), 256, 0, stream>>>(
      WTb, WTb, Ef, Eb, nullptr, lr, 0.f, 3072, 768);
  // 3. Spb = bf16(120*(Eb@Eb^T) - 45*Ef) : K=768, 12 iters (72 blocks)
  gemm_pipe<4><<<dim3(12, 6), 256, 0, stream>>>(
      Eb, Eb, Ef, Spb, nullptr, 120.f, -45.f, 768, 768);
  // 4. WMTb = bf16(lr*Spb@Wb^T + 0.01*WTb) : K=768, 12 iters (288 blocks)
  gemm_pipe<3><<<dim3(12, 24), 256, 0, stream>>>(
      Spb, Wb, nullptr, WMTb, WTb, lr, 0.01f, 768, 3072);
  // 5. out = tb @ WMT^T : grid 128x6 = 768 blocks = 3/CU, pipelined
  gemm_pipe<6><<<dim3(128, 6), 256, 0, stream>>>(
      tb, WMTb, out, nullptr, nullptr, 1.f, 0.f, 3072, 768);
}

// Round 9
// 270.746 us; speedup vs baseline: 1.3833x; 1.0182x over previous
//
#include <hip/hip_runtime.h>
#include <stdint.h>

// PCLayer closed form, 5-launch route (r9):
//   conv_all : tb = bf16(t-b) [8192,3072], WTb = bf16(W)^T, Wb = bf16(W)
//   E        : Ef(fp32)+Eb(bf16) = lr * WTb @ WTb^T   (EPI 5)
//   S''      : Spb = bf16(120*(Eb@Eb^T) - 45*Ef)      (EPI 4)
//   WMT      : WMTb = bf16(lr*Spb@Wb^T + 0.01*WTb)    (EPI 3)
//   big      : out = tb @ WMT^T  [8192,768] fp32      (128x128 pipelined)
// r9 vs r8: ONE change — big GEMM tile 64x128 -> 128x128 at the SAME
// (now-proven) single-barrier late-drain pipeline. Rationale: r8 fixed the
// structure (62.6us, first beat of r1's 66.5) but per-wave-iter ratio was
// 12 ds_read_b128 : 16 MFMA; 128^2 gives 16 : 32 (33% less LDS traffic
// per FLOP — the m97-ladder 64^2=343 vs 128^2=912 lever). LDS 64KB ->
// 2 blocks/CU, grid 64x6=384 <= 512 slots -> whole grid co-resident
// (6 y-blocks per x share the A-panel in L2).
// Cross-round accounting: total-minus-kernels ~= 150us fixed (harness
// restore dispatches; independent of our launch count) -> controllable
// budget ~126us, of which big GEMM is 63. Small chain untouched.

typedef short bf16x8 __attribute__((ext_vector_type(8)));   // 8 bf16 = 4 VGPRs
typedef float f32x4  __attribute__((ext_vector_type(4)));
typedef unsigned short u16;
typedef unsigned int uint_as1 __attribute__((address_space(1)));
typedef unsigned int uint_as3 __attribute__((address_space(3)));

__device__ __forceinline__ float bf2f(u16 u) {
  union { unsigned int i; float f; } x; x.i = ((unsigned int)u) << 16; return x.f;
}
__device__ __forceinline__ u16 f2bf(float f) {  // round-to-nearest-even
  union { float f; unsigned int i; } x; x.f = f;
  unsigned int r = x.i + 0x7fffu + ((x.i >> 16) & 1u);
  return (u16)(r >> 16);
}
__device__ __forceinline__ void gl2lds16(const void* g, void* l) {
  // async 16B/lane global->LDS; LDS dst = wave-uniform base + lane*16
  __builtin_amdgcn_global_load_lds((uint_as1*)(uintptr_t)g,
                                   (uint_as3*)(uintptr_t)l, 16, 0, 0);
}

// ---- pipelined small GEMM (r8-proven): C = alpha * A[M,K] @ B[N,K]^T,
// tile 64x128, 4 waves 2x2, BK=64, double-buffered LDS, 1 barrier/iter,
// late vmcnt drain.
// EPI 3: Cb = f2bf(alpha*acc + beta*bf2f(Yb[idx]))
// EPI 4: Cb = f2bf(alpha*acc + beta*Cf[idx])        (Cf read-only fp32)
// EPI 5: Cf = alpha*acc (fp32)  AND  Cb = f2bf(same)
template<int EPI>
__global__ __launch_bounds__(256, 3)
void gemm_pipe(const u16* __restrict__ A, const u16* __restrict__ B,
               float* __restrict__ Cf, u16* __restrict__ Cb,
               const u16* __restrict__ Yb, float alpha, float beta,
               int K, int ldc)
{
  __shared__ u16 As[2][64 * 64];    // 2 x 8KB
  __shared__ u16 Bs[2][128 * 64];   // 2 x 16KB
  const int tid = threadIdx.x, w = tid >> 6, lane = tid & 63;
  const int lm = lane & 15, quad = lane >> 4;
  const int wm = w & 1, wn = w >> 1;
  const int m0 = blockIdx.x * 64, n0 = blockIdx.y * 128;
  const int r = lane >> 2, q = lane & 3;
  const u16* Ag = A + (long)(m0 + w * 16 + r) * K + q * 8;
  const u16* Bg = B + (long)(n0 + w * 32 + r) * K + q * 8;
  const int nIter = K >> 6;

  f32x4 acc[2][4] = {};

#define STAGE_S(kk, b)                                                       \
  {                                                                          \
    _Pragma("unroll")                                                        \
    for (int h = 0; h < 2; ++h) {                                            \
      gl2lds16(Ag + (kk) + h * 32, As[b] + w * 512 + h * 2048);              \
      gl2lds16(Bg + (kk) + h * 32, Bs[b] + w * 1024 + h * 4096);             \
      gl2lds16(Bg + 16 * (long)K + (kk) + h * 32,                            \
               Bs[b] + w * 1024 + h * 4096 + 512);                           \
    }                                                                        \
  }

  STAGE_S(0, 0)
  asm volatile("s_waitcnt vmcnt(0)" ::: "memory");
  __builtin_amdgcn_sched_barrier(0);
  __builtin_amdgcn_s_barrier();
  __builtin_amdgcn_sched_barrier(0);

  int cur = 0;
  for (int k = 0; k < nIter; ++k) {
    if (k + 1 < nIter) STAGE_S((k + 1) * 64, cur ^ 1)   // issue early
    const u16* Asb = As[cur];
    const u16* Bsb = Bs[cur];
#pragma unroll
    for (int h = 0; h < 2; ++h) {
      bf16x8 af[2], bv[4];
#pragma unroll
      for (int i = 0; i < 2; ++i)
        af[i] = *(const bf16x8*)(Asb + h * 2048 +
                                 (wm * 32 + i * 16 + lm) * 32 + quad * 8);
#pragma unroll
      for (int j = 0; j < 4; ++j)
        bv[j] = *(const bf16x8*)(Bsb + h * 4096 +
                                 (wn * 64 + j * 16 + lm) * 32 + quad * 8);
#pragma unroll
      for (int i = 0; i < 2; ++i)
#pragma unroll
        for (int j = 0; j < 4; ++j)
          acc[i][j] = __builtin_amdgcn_mfma_f32_16x16x32_bf16(af[i], bv[j],
                                                              acc[i][j], 0, 0, 0);
    }
    if (k + 1 < nIter) {
      asm volatile("s_waitcnt vmcnt(0)" ::: "memory");   // drain LATE
      __builtin_amdgcn_sched_barrier(0);
      __builtin_amdgcn_s_barrier();
      __builtin_amdgcn_sched_barrier(0);
      cur ^= 1;
    }
  }
#undef STAGE_S

  // C/D layout (m89-verified): col = lane&15, row = quad*4 + reg
  const int rbase = m0 + wm * 32 + quad * 4;
  const int cbase = n0 + wn * 64 + lm;
#pragma unroll
  for (int i = 0; i < 2; ++i)
#pragma unroll
    for (int j = 0; j < 4; ++j) {
      const int col = cbase + j * 16;
#pragma unroll
      for (int rr = 0; rr < 4; ++rr) {
        const long idx = (long)(rbase + i * 16 + rr) * ldc + col;
        const float v = alpha * acc[i][j][rr];
        if constexpr (EPI == 3) {
          Cb[idx] = f2bf(v + beta * bf2f(Yb[idx]));
        } else if constexpr (EPI == 4) {
          Cb[idx] = f2bf(v + beta * Cf[idx]);
        } else {  // EPI 5
          Cf[idx] = v;
          Cb[idx] = f2bf(v);
        }
      }
    }
}

// ---- big GEMM: out[8192,768] = tb @ WMT^T (fp32). Tile 128x128, 4 waves
// 2x2 (wave = 64x64, 4x4 fragments), BK=64, r8's single-barrier late-drain
// pipeline. Per wave-iter: 8 gl2lds stage, 16 ds_read_b128, 32 MFMA.
// LDS 2 x (16KB A + 16KB B) = 64KB -> 2 blocks/CU; grid 64x6 = 384 blocks,
// all co-resident (<= 512 slots).
__global__ __launch_bounds__(256, 2)
void gemm_big(const u16* __restrict__ A, const u16* __restrict__ B,
              float* __restrict__ out)
{
  __shared__ u16 As[2][2 * 128 * 32];   // 2 x 16KB [buf][h][row128][k32]
  __shared__ u16 Bs[2][2 * 128 * 32];   // 2 x 16KB
  const int tid = threadIdx.x, w = tid >> 6, lane = tid & 63;
  const int lm = lane & 15, quad = lane >> 4;
  const int wm = w & 1, wn = w >> 1;
  const int m0 = blockIdx.x * 128, n0 = blockIdx.y * 128;
  const int r = lane >> 2, q = lane & 3;
  const u16* Ag = A + (long)(m0 + w * 32 + r) * 3072 + q * 8;
  const u16* Bg = B + (long)(n0 + w * 32 + r) * 3072 + q * 8;

  f32x4 acc[4][4] = {};

  // wave w stages rows w*32..w*32+31 of A and of B (2 x 16-row gl2lds per h)
#define STAGE_B(kk, b)                                                        \
  {                                                                           \
    _Pragma("unroll")                                                         \
    for (int h = 0; h < 2; ++h) {                                             \
      gl2lds16(Ag + (kk) + h * 32,              As[b] + h * 4096 + w * 1024); \
      gl2lds16(Ag + 16L * 3072 + (kk) + h * 32,                               \
               As[b] + h * 4096 + w * 1024 + 512);                            \
      gl2lds16(Bg + (kk) + h * 32,              Bs[b] + h * 4096 + w * 1024); \
      gl2lds16(Bg + 16L * 3072 + (kk) + h * 32,                               \
               Bs[b] + h * 4096 + w * 1024 + 512);                            \
    }                                                                         \
  }

  STAGE_B(0, 0)
  asm volatile("s_waitcnt vmcnt(0)" ::: "memory");
  __builtin_amdgcn_sched_barrier(0);
  __builtin_amdgcn_s_barrier();
  __builtin_amdgcn_sched_barrier(0);

  int cur = 0;
  for (int k = 0; k < 48; ++k) {
    if (k + 1 < 48) STAGE_B((k + 1) * 64, cur ^ 1)   // issue early
    const u16* Asb = As[cur];
    const u16* Bsb = Bs[cur];
#pragma unroll
    for (int h = 0; h < 2; ++h) {
      bf16x8 af[4], bv[4];
#pragma unroll
      for (int i = 0; i < 4; ++i)
        af[i] = *(const bf16x8*)(Asb + h * 4096 +
                                 (wm * 64 + i * 16 + lm) * 32 + quad * 8);
#pragma unroll
      for (int j = 0; j < 4; ++j)
        bv[j] = *(const bf16x8*)(Bsb + h * 4096 +
                                 (wn * 64 + j * 16 + lm) * 32 + quad * 8);
#pragma unroll
      for (int i = 0; i < 4; ++i)
#pragma unroll
        for (int j = 0; j < 4; ++j)
          acc[i][j] = __builtin_amdgcn_mfma_f32_16x16x32_bf16(af[i], bv[j],
                                                              acc[i][j], 0, 0, 0);
    }
    if (k + 1 < 48) {
      asm volatile("s_waitcnt vmcnt(0)" ::: "memory");   // drain LATE
      __builtin_amdgcn_sched_barrier(0);
      __builtin_amdgcn_s_barrier();
      __builtin_amdgcn_sched_barrier(0);
      cur ^= 1;
    }
  }
#undef STAGE_B

  // C/D layout (m89-verified): col = lane&15, row = quad*4 + reg
  const int rbase = m0 + wm * 64 + quad * 4;
  const int cbase = n0 + wn * 64 + lm;
#pragma unroll
  for (int i = 0; i < 4; ++i)
#pragma unroll
    for (int j = 0; j < 4; ++j)
#pragma unroll
      for (int rr = 0; rr < 4; ++rr)
        out[(long)(rbase + i * 16 + rr) * 768 + cbase + j * 16] =
            acc[i][j][rr];
}

// ---- conv_all (r1-proven): tb = bf16(t - b) [blocks 0..24575];
// WTb = bf16(W)^T via LDS-tiled transpose + Wb = bf16(W) [blocks 24576..25151]
__global__ void conv_all(const float* __restrict__ t, const float* __restrict__ bias,
                         const float* __restrict__ W, u16* __restrict__ tb,
                         u16* __restrict__ WTb, u16* __restrict__ Wb)
{
  __shared__ u16 lds[64 * 72];              // [i_local][o_local], stride 72
  const int bx = blockIdx.x, tid = threadIdx.x;
  if (bx < 24576) {                         // t: 6,291,456 float4
    const long i4 = (long)bx * 256 + tid;
    const float4 v = ((const float4*)t)[i4];
    const float4 bb = ((const float4*)bias)[(int)(i4 % 768)];
    ushort4 o;
    o.x = f2bf(v.x - bb.x); o.y = f2bf(v.y - bb.y);
    o.z = f2bf(v.z - bb.z); o.w = f2bf(v.w - bb.w);
    ((ushort4*)tb)[i4] = o;
  } else {
    const int bt = bx - 24576;              // tile (to, ti): o0 = to*64, i0 = ti*64
    const int o0 = (bt / 12) * 64, i0 = (bt % 12) * 64;
    const int ol = tid >> 2, cg = tid & 3;  // 64 o-rows, 4 col-groups
#pragma unroll
    for (int p = 0; p < 4; ++p) {           // 16 float4 per o-row
      const float4 v = *(const float4*)(W + (long)(o0 + ol) * 768 + i0 + (cg + p * 4) * 4);
      const int ib = (cg + p * 4) * 4;
      lds[(ib + 0) * 72 + ol] = f2bf(v.x);
      lds[(ib + 1) * 72 + ol] = f2bf(v.y);
      lds[(ib + 2) * 72 + ol] = f2bf(v.z);
      lds[(ib + 3) * 72 + ol] = f2bf(v.w);
      ushort4 wo;
      wo.x = f2bf(v.x); wo.y = f2bf(v.y); wo.z = f2bf(v.z); wo.w = f2bf(v.w);
      ((ushort4*)(Wb + (long)(o0 + ol) * 768 + i0))[cg + p * 4] = wo;
    }
    __syncthreads();
    const int cl = tid >> 2, og = tid & 3;  // 64 i-rows, 4 o-groups of 16
    const u16* src = lds + cl * 72 + og * 16;
    u16* dst = WTb + (long)(i0 + cl) * 3072 + o0 + og * 16;
    ((ushort4*)dst)[0] = ((const ushort4*)src)[0];
    ((ushort4*)dst)[1] = ((const ushort4*)src)[1];
    ((ushort4*)dst)[2] = ((const ushort4*)src)[2];
    ((ushort4*)dst)[3] = ((const ushort4*)src)[3];
  }
}

extern "C" void kernel_launch(void* const* d_in, const int* in_sizes, int n_in,
                              void* d_out, int out_size, void* d_ws, size_t ws_size,
                              hipStream_t stream)
{
  const float* t    = (const float*)d_in[0];   // [8,1024,3072]
  const float* W    = (const float*)d_in[1];   // [3072,768]
  const float* bias = (const float*)d_in[2];   // [3072]
  float* out = (float*)d_out;                  // [8192,768] fp32

  char* p = (char*)d_ws;                       // 69,206,016 B used
  u16*   tb   = (u16*)(p + 0);                 // 50,331,648  bf16 t-b  [8192,3072]
  u16*   WTb  = (u16*)(p + 50331648);          //  4,718,592  bf16 W^T  [768,3072]
  u16*   Wb   = (u16*)(p + 55050240);          //  4,718,592  bf16 W    [3072,768]
  float* Ef   = (float*)(p + 59768832);        //  2,359,296  E fp32    [768,768]
  u16*   Eb   = (u16*)(p + 62128128);          //  1,179,648  bf16 E
  u16*   Spb  = (u16*)(p + 63307776);          //  1,179,648  bf16 S''
  u16*   WMTb = (u16*)(p + 64487424);          //  4,718,592  bf16 WMT [768,3072]

  const float lr = 0.001f;

  // 1. tb + WTb + Wb  (24576 conv blocks + 576 transpose tiles)
  conv_all<<<25152, 256, 0, stream>>>(t, bias, W, tb, WTb, Wb);
  // 2. Ef,Eb = lr * WT @ WT^T : K=3072, 48 pipelined iters (72 blocks)
  gemm_pipe<5><<<dim3(12, 6), 256, 0, stream>>>(
      WTb, WTb, Ef, Eb, nullptr, lr, 0.f, 3072, 768);
  // 3. Spb = bf16(120*(Eb@Eb^T) - 45*Ef) : K=768, 12 iters (72 blocks)
  gemm_pipe<4><<<dim3(12, 6), 256, 0, stream>>>(
      Eb, Eb, Ef, Spb, nullptr, 120.f, -45.f, 768, 768);
  // 4. WMTb = bf16(lr*Spb@Wb^T + 0.01*WTb) : K=768, 12 iters (288 blocks)
  gemm_pipe<3><<<dim3(12, 24), 256, 0, stream>>>(
      Spb, Wb, nullptr, WMTb, WTb, lr, 0.01f, 768, 3072);
  // 5. out = tb @ WMT^T : 128x128 tile, grid 64x6 = 384 blocks (2/CU, all
  //    co-resident), single-barrier late-drain pipeline
  gemm_big<<<dim3(64, 6), 256, 0, stream>>>(tb, WMTb, out);
}